// Round 10
// baseline (7099.166 us; speedup 1.0000x reference)
//
#include <hip/hip_runtime.h>
#include <math.h>

#define BATCH 16
#define T 512
#define NT 6
#define START 4
#define STOP 5
#define NEGV -10000.0f
#define LOG2E 1.4426950408889634f

typedef __attribute__((ext_vector_type(8))) short short8;
typedef __attribute__((ext_vector_type(4))) float f32x4;
typedef __attribute__((ext_vector_type(4))) int i32x4;

__device__ __forceinline__ float fast_sig(float x) {
    float e = __builtin_amdgcn_exp2f(-LOG2E * x);
    return __builtin_amdgcn_rcpf(1.f + e);
}
__device__ __forceinline__ float fast_tanh(float x) {
    float e = __builtin_amdgcn_exp2f(-2.f * LOG2E * x);
    return (1.f - e) * __builtin_amdgcn_rcpf(1.f + e);
}
__device__ __forceinline__ unsigned bf16_rne(float f) {
    unsigned u = __builtin_bit_cast(unsigned, f);
    u += 0x7FFFu + ((u >> 16) & 1u);
    return u >> 16;
}
// LDS-only barrier: does NOT drain vmcnt -> prefetches/publishes/gathers stay in flight.
__device__ __forceinline__ void bar_lds() {
    asm volatile("s_waitcnt lgkmcnt(0)" ::: "memory");
    __builtin_amdgcn_sched_barrier(0);
    __builtin_amdgcn_s_barrier();
}

// ws layout (float units):
//   [0, 8388608)        Xp2 fp32 [t][k][n][lane][j]  (32 MB)
//                       Hg u64[512][16][128] ALIASES first 8MB: unit = {2 bf16 h | tag<<32},
//                       tag of page p = p+1. Publishes for page t-1 (at step t) trail Xp2
//                       reads (64KB*t) by 4x -> no clobber. fp32 bit patterns / 0xAA poison
//                       never equal a valid tag; input_proj rewrites region every call so
//                       stale tags from a previous replay are erased before lstm runs.
//   [8388608, 8650752)  WihT fp32 (dead after input_proj; Xp prefetch overruns here: benign)
//   [8650752, 8781824)  Wf bf16 MFMA B-fragments (512 KB)
//   [8781824, 8830976)  feats fp32 [b][t][6]

__global__ void transpose_wih(const float* __restrict__ W_ih, float* __restrict__ WihT) {
    int o = blockIdx.x * blockDim.x + threadIdx.x;
    if (o >= 256 * 1024) return;
    int k = o >> 10;
    int g = o & 1023;
    WihT[o] = W_ih[g * 256 + k];
}

// Pack W_hh (fp32 [1024][256]) into bf16 MFMA B-fragments.
// flat frag f = ((K*4+n)*8+kt); lane l: g = n*256 + K*16 + (l&15), kk = kt*32 + (l>>4)*8 + j
__global__ void wf_prep(const float* __restrict__ W_hh, unsigned short* __restrict__ Wf) {
    int t = blockIdx.x * 256 + threadIdx.x;  // 0..32767
    int l = t & 63, kt = (t >> 6) & 7, n = (t >> 9) & 3, w = t >> 11;
    int g = n * 256 + w * 16 + (l & 15);
    int kk = kt * 32 + (l >> 4) * 8;
    const float* src = W_hh + g * 256 + kk;
    unsigned short* dst = Wf + (size_t)t * 8;
#pragma unroll
    for (int j = 0; j < 8; j++) dst[j] = (unsigned short)bf16_rne(src[j]);
}

// One block = 16 (b,t) rows, 1024 threads = 1 per gate. Writes Xp2 in MFMA C-layout.
__global__ __launch_bounds__(1024) void input_proj(const int* __restrict__ sentence,
                                                   const float* __restrict__ embedding,
                                                   const float* __restrict__ WihT,
                                                   const float* __restrict__ b_ih,
                                                   const float* __restrict__ b_hh,
                                                   float* __restrict__ Xp2) {
    __shared__ __align__(16) float emb[16][260];
    int tid = threadIdx.x;
    int bt0 = blockIdx.x * 16;
    {
        int r = tid >> 6, j = tid & 63;
        int row = sentence[bt0 + r];
        const float4* src = (const float4*)(embedding + (size_t)row * 256);
        float4 v = src[j];
        float* dst = &emb[r][j * 4];
        dst[0] = v.x; dst[1] = v.y; dst[2] = v.z; dst[3] = v.w;
    }
    __syncthreads();
    int g = tid;
    float bias = b_ih[g] + b_hh[g];
    float acc[16];
#pragma unroll
    for (int r = 0; r < 16; r++) acc[r] = bias;
    const float* wp = WihT + g;
    for (int k4 = 0; k4 < 64; k4++) {
        float w0 = wp[(k4 * 4 + 0) * 1024];
        float w1 = wp[(k4 * 4 + 1) * 1024];
        float w2 = wp[(k4 * 4 + 2) * 1024];
        float w3 = wp[(k4 * 4 + 3) * 1024];
#pragma unroll
        for (int r = 0; r < 16; r++) {
            float4 e = *(const float4*)&emb[r][k4 * 4];
            acc[r] += w0 * e.x + w1 * e.y + w2 * e.z + w3 * e.w;
        }
    }
    int b = bt0 >> 9, t0 = bt0 & 511;
    int q = b >> 2, j = b & 3;
    int n = g >> 8, u = g & 255, k = u >> 4, cc = u & 15;
    int lane = q * 16 + cc;
#pragma unroll
    for (int r = 0; r < 16; r++) {
        int t = t0 + r;
        Xp2[(size_t)(((t * 16 + k) * 4 + n) * 64 + lane) * 4 + j] = acc[r];
    }
}

// 2 blocks x 512 threads (8 waves). Block SIDE owns h-units [SIDE*128, +128):
// W slice = 128 VGPR/thread bf16 (register-resident). Wave w computes all 4 gates for
// units SIDE*128 + w*16 + c -> lane-local c/h update. Own half exchanged via XOR-swizzled
// LDS (one LDS-only barrier/step); remote half via tagged {h,h,tag} u64 pages, loads
// issued at top of step and validated AFTER own-half MFMAs (RTT hidden under compute).
__global__ __launch_bounds__(512, 2) void lstm_mfma(const unsigned short* __restrict__ Wf,
                                                    const float* Xp2,
                                                    unsigned long long* Hg) {
    __shared__ unsigned short hbuf[2][2048];  // [parity][b=16][lc=128] bf16, XOR-swizzled
    int tid = threadIdx.x;
    int SIDE = blockIdx.x;
    int w = tid >> 6, l = tid & 63;
    int q = l >> 4, c = l & 15;
    int K = SIDE * 8 + w;  // global unit-group (16 units each)

    // B-fragments, all 8 k-frags for this wave's 4 gate tiles: 32 x short8 = 128 VGPR
    short8 wr[4][8];
#pragma unroll
    for (int n = 0; n < 4; n++)
#pragma unroll
        for (int kt = 0; kt < 8; kt++)
            wr[n][kt] = *(const short8*)(Wf + ((size_t)((K * 4 + n) * 8 + kt) * 64 + l) * 8);

    const char* xbase = (const char*)Xp2 + ((size_t)K * 4) * 1024 + (size_t)l * 16;
    f32x4 xv[4];
#pragma unroll
    for (int n = 0; n < 4; n++) xv[n] = *(const f32x4*)(xbase + n * 1024);

    float c_st[4] = {0.f, 0.f, 0.f, 0.f};
    int lc = w * 16 + c;  // local col of this lane's owned units

    // publisher mapping (per thread): row pb, unit-pair mpair
    int pb = tid & 15, mpair = tid >> 4;  // mpair 0..31
    int pub_byte = (pb * 256 + mpair * 8) ^ ((pb & 7) << 4);
    int pub_unit = pb * 128 + SIDE * 64 + mpair * 2;
    // remote gather base (u64 idx): row b=l&15, remote ktg = (1-SIDE)*4 + ktl
    int rem_base = (l & 15) * 128 + ((1 - SIDE) * 4) * 16 + q * 4;
    // own A-frag LDS read base (bytes, pre-ktl)
    int rowq = (l & 15) * 256 + q * 16;
    int sw = (l & 7) << 4;

    for (int t = 0; t < T; t++) {
        unsigned long long vv[4][4];
        const unsigned long long* pg = Hg + (size_t)(t - 1) * 2048 + rem_base;
        const char* hb = (const char*)hbuf[(t - 1) & 1];
        if (t > 0) {
            bar_lds();  // own h(t-1) in LDS; prior LDS reads done
            // publish own h(t-1) half from LDS (fire-and-forget, 2 u64/thread)
            {
                uint2 pv = *(const uint2*)(hb + pub_byte);
                unsigned long long tagw = (unsigned long long)(unsigned)t << 32;
                unsigned long long* page = Hg + (size_t)(t - 1) * 2048;
                __hip_atomic_store(page + pub_unit + 0, (unsigned long long)pv.x | tagw,
                                   __ATOMIC_RELAXED, __HIP_MEMORY_SCOPE_AGENT);
                __hip_atomic_store(page + pub_unit + 1, (unsigned long long)pv.y | tagw,
                                   __ATOMIC_RELAXED, __HIP_MEMORY_SCOPE_AGENT);
            }
            // issue remote gather (validated after own-half MFMAs)
#pragma unroll
            for (int ktl = 0; ktl < 4; ktl++)
#pragma unroll
                for (int e = 0; e < 4; e++)
                    vv[ktl][e] = __hip_atomic_load(pg + ktl * 16 + e, __ATOMIC_RELAXED,
                                                   __HIP_MEMORY_SCOPE_AGENT);
            __builtin_amdgcn_sched_barrier(0);
        }

        f32x4 acc[4];
#pragma unroll
        for (int n = 0; n < 4; n++) acc[n] = xv[n];

        // prefetch Xp[t+1] (consumed next iter; never force-drained)
        f32x4 xn[4];
        if (t + 1 < T) {
            const char* xb1 = xbase + (size_t)(t + 1) * 65536;
#pragma unroll
            for (int n = 0; n < 4; n++) xn[n] = *(const f32x4*)(xb1 + n * 1024);
        }

        if (t > 0) {
            // own-half MFMAs (A from LDS) — covers the remote loads' LLC RTT
#pragma unroll
            for (int ktl = 0; ktl < 4; ktl++) {
                short8 a = *(const short8*)(hb + ((rowq + ktl * 64) ^ sw));
#pragma unroll
                for (int n = 0; n < 4; n++)
                    acc[n] = __builtin_amdgcn_mfma_f32_16x16x32_bf16(a, wr[n][SIDE * 4 + ktl],
                                                                     acc[n], 0, 0, 0);
            }
            // validate remote tags; rare retry with backoff (2-party, no storms)
            while (true) {
                bool ok = true;
#pragma unroll
                for (int ktl = 0; ktl < 4; ktl++)
#pragma unroll
                    for (int e = 0; e < 4; e++)
                        ok = ok & ((unsigned)(vv[ktl][e] >> 32) == (unsigned)t);
                if (__all(ok)) break;
                asm volatile("s_sleep 1");
#pragma unroll
                for (int ktl = 0; ktl < 4; ktl++)
#pragma unroll
                    for (int e = 0; e < 4; e++)
                        vv[ktl][e] = __hip_atomic_load(pg + ktl * 16 + e, __ATOMIC_RELAXED,
                                                       __HIP_MEMORY_SCOPE_AGENT);
            }
#pragma unroll
            for (int ktl = 0; ktl < 4; ktl++) {
                i32x4 pk = {(int)vv[ktl][0], (int)vv[ktl][1], (int)vv[ktl][2], (int)vv[ktl][3]};
                short8 a = __builtin_bit_cast(short8, pk);
#pragma unroll
                for (int n = 0; n < 4; n++)
                    acc[n] = __builtin_amdgcn_mfma_f32_16x16x32_bf16(
                        a, wr[n][(1 - SIDE) * 4 + ktl], acc[n], 0, 0, 0);
            }
        }

        // lane-local activations; write own h(t) to LDS buf[t&1] (swizzled)
        char* hw = (char*)hbuf[t & 1];
#pragma unroll
        for (int j = 0; j < 4; j++) {
            float iv = fast_sig(acc[0][j]);
            float fg = fast_sig(acc[1][j]);
            float gv = fast_tanh(acc[2][j]);
            float ov = fast_sig(acc[3][j]);
            c_st[j] = fg * c_st[j] + iv * gv;
            unsigned hval = bf16_rne(ov * fast_tanh(c_st[j]));
            int b = q * 4 + j;
            *(unsigned short*)(hw + ((b * 256 + lc * 2) ^ ((b & 7) << 4))) = (unsigned short)hval;
        }
#pragma unroll
        for (int n = 0; n < 4; n++) xv[n] = xn[n];
    }

    // epilogue: publish h(T-1) (page T-1) for feats_k
    bar_lds();
    {
        const char* hb = (const char*)hbuf[(T - 1) & 1];
        uint2 pv = *(const uint2*)(hb + pub_byte);
        unsigned long long tagw = (unsigned long long)(unsigned)T << 32;
        unsigned long long* page = Hg + (size_t)(T - 1) * 2048;
        __hip_atomic_store(page + pub_unit + 0, (unsigned long long)pv.x | tagw,
                           __ATOMIC_RELAXED, __HIP_MEMORY_SCOPE_AGENT);
        __hip_atomic_store(page + pub_unit + 1, (unsigned long long)pv.y | tagw,
                           __ATOMIC_RELAXED, __HIP_MEMORY_SCOPE_AGENT);
    }
}

// feats[b][t][tag] = h(b,t) . W_out[tag] + b_out[tag].  2048 blocks x 256, wave = one (b,t).
__global__ __launch_bounds__(256) void feats_k(const unsigned long long* __restrict__ Hg,
                                               const float* __restrict__ W_out,
                                               const float* __restrict__ b_out,
                                               float* __restrict__ feats) {
    int wid = blockIdx.x * 4 + (threadIdx.x >> 6);
    int l = threadIdx.x & 63;
    int b = wid >> 9, t = wid & 511;
    // lane l covers u = l*4 + {0..3} -> units b*128 + 2l, 2l+1 -> one 16B load
    const uint4* src = (const uint4*)(Hg + (size_t)t * 2048 + b * 128) + l;
    uint4 v = *src;
    float h0 = __builtin_bit_cast(float, (v.x & 0xffffu) << 16);
    float h1 = __builtin_bit_cast(float, v.x & 0xffff0000u);
    float h2 = __builtin_bit_cast(float, (v.z & 0xffffu) << 16);
    float h3 = __builtin_bit_cast(float, v.z & 0xffff0000u);
    int ub = l * 4;
#pragma unroll
    for (int tag = 0; tag < 6; tag++) {
        float4 wv = *(const float4*)(W_out + tag * 256 + ub);
        float p = h0 * wv.x + h1 * wv.y + h2 * wv.z + h3 * wv.w;
#pragma unroll
        for (int off = 32; off; off >>= 1) p += __shfl_down(p, off);
        if (l == 0) feats[((size_t)b * 512 + t) * 6 + tag] = p + b_out[tag];
    }
}

// 16 blocks x 64 threads. Lane nx owns next-tag nx; fv broadcast via shfl each step.
__global__ __launch_bounds__(64) void crf_scan(const float* __restrict__ feats,
                                               const float* __restrict__ trans,
                                               float* __restrict__ out) {
    __shared__ float fl[T * 6];
    __shared__ unsigned char bp[T * 8];
    int b = blockIdx.x, tid = threadIdx.x;
    const float4* src = (const float4*)(feats + (size_t)b * 3072);
#pragma unroll
    for (int i = 0; i < 12; i++) ((float4*)fl)[tid + i * 64] = src[tid + i * 64];
    int nx = (tid < 6) ? tid : 0;
    float tr0 = trans[nx * 6 + 0], tr1 = trans[nx * 6 + 1], tr2 = trans[nx * 6 + 2],
          tr3 = trans[nx * 6 + 3], tr4 = trans[nx * 6 + 4], tr5 = trans[nx * 6 + 5];
    float fv0 = NEGV, fv1 = NEGV, fv2 = NEGV, fv3 = NEGV, fv4 = 0.f, fv5 = NEGV;  // START=4
    __syncthreads();
    for (int t = 0; t < T; t++) {
        float best = fv0 + tr0; int arg = 0; float s;
        s = fv1 + tr1; if (s > best) { best = s; arg = 1; }
        s = fv2 + tr2; if (s > best) { best = s; arg = 2; }
        s = fv3 + tr3; if (s > best) { best = s; arg = 3; }
        s = fv4 + tr4; if (s > best) { best = s; arg = 4; }
        s = fv5 + tr5; if (s > best) { best = s; arg = 5; }  // strict >: first-max
        float nf = best + fl[t * 6 + nx];
        if (tid < 6) bp[t * 8 + tid] = (unsigned char)arg;
        fv0 = __shfl(nf, 0); fv1 = __shfl(nf, 1); fv2 = __shfl(nf, 2);
        fv3 = __shfl(nf, 3); fv4 = __shfl(nf, 4); fv5 = __shfl(nf, 5);
    }
    __syncthreads();
    if (tid == 0) {
        float best = fv0 + trans[STOP * 6 + 0]; int arg = 0; float s;
        s = fv1 + trans[STOP * 6 + 1]; if (s > best) { best = s; arg = 1; }
        s = fv2 + trans[STOP * 6 + 2]; if (s > best) { best = s; arg = 2; }
        s = fv3 + trans[STOP * 6 + 3]; if (s > best) { best = s; arg = 3; }
        s = fv4 + trans[STOP * 6 + 4]; if (s > best) { best = s; arg = 4; }
        s = fv5 + trans[STOP * 6 + 5]; if (s > best) { best = s; arg = 5; }
        out[b] = best;
        int tag = arg;
        float* paths = out + 16 + (size_t)b * 512;
        for (int t = T - 1; t >= 0; t--) {
            paths[t] = (float)tag;
            tag = bp[t * 8 + tag];
        }
    }
}

extern "C" void kernel_launch(void* const* d_in, const int* in_sizes, int n_in,
                              void* d_out, int out_size, void* d_ws, size_t ws_size,
                              hipStream_t stream) {
    const int* sentence = (const int*)d_in[0];
    const float* embedding = (const float*)d_in[1];
    const float* W_ih = (const float*)d_in[2];
    const float* W_hh = (const float*)d_in[3];
    const float* b_ih = (const float*)d_in[4];
    const float* b_hh = (const float*)d_in[5];
    const float* W_out = (const float*)d_in[6];
    const float* b_out = (const float*)d_in[7];
    const float* trans = (const float*)d_in[8];
    float* out = (float*)d_out;
    float* ws = (float*)d_ws;

    float* Xp2 = ws;
    unsigned long long* Hg = (unsigned long long*)ws;  // aliases Xp2 head (consumed region)
    float* WihT = ws + 8388608;
    unsigned short* Wf = (unsigned short*)(ws + 8650752);
    float* feats = ws + 8781824;

    hipLaunchKernelGGL(transpose_wih, dim3(1024), dim3(256), 0, stream, W_ih, WihT);
    hipLaunchKernelGGL(input_proj, dim3(BATCH * T / 16), dim3(1024), 0, stream,
                       sentence, embedding, WihT, b_ih, b_hh, Xp2);
    hipLaunchKernelGGL(wf_prep, dim3(128), dim3(256), 0, stream, W_hh, Wf);
    hipLaunchKernelGGL(lstm_mfma, dim3(2), dim3(512), 0, stream, Wf, Xp2, Hg);
    hipLaunchKernelGGL(feats_k, dim3(2048), dim3(256), 0, stream, Hg, W_out, b_out, feats);
    hipLaunchKernelGGL(crf_scan, dim3(BATCH), dim3(64), 0, stream, feats, trans, out);
}

// Round 12
// 1290.156 us; speedup vs baseline: 5.5026x; 5.5026x over previous
//
#include <hip/hip_runtime.h>
#include <math.h>

#define HDIM 256
#define BATCH 16
#define T 512
#define NT 6
#define START 4
#define STOP 5
#define NEGV -10000.0f
#define LOG2E 1.4426950408889634f
#define NBLK 16  // lstm blocks; block k owns gate cols {n*256 + k*16 + c}

typedef __attribute__((ext_vector_type(8))) short short8;
typedef __attribute__((ext_vector_type(4))) float f32x4;
typedef __attribute__((ext_vector_type(4))) int i32x4;

union U16B { unsigned long long u[2]; short8 s; };
union UPK { unsigned short s[4]; unsigned long long u; };

__device__ __forceinline__ float fast_sig(float x) {
    float e = __builtin_amdgcn_exp2f(-LOG2E * x);
    return __builtin_amdgcn_rcpf(1.f + e);
}
__device__ __forceinline__ float fast_tanh(float x) {
    float e = __builtin_amdgcn_exp2f(-2.f * LOG2E * x);
    return (1.f - e) * __builtin_amdgcn_rcpf(1.f + e);
}
__device__ __forceinline__ unsigned short bf16_rne(float f) {
    unsigned u = __builtin_bit_cast(unsigned, f);
    u += 0x7FFFu + ((u >> 16) & 1u);
    return (unsigned short)(u >> 16);
}
// LDS-only barrier: does NOT drain vmcnt -> prefetches/publishes stay in flight.
__device__ __forceinline__ void bar_lds() {
    asm volatile("s_waitcnt lgkmcnt(0)" ::: "memory");
    __builtin_amdgcn_sched_barrier(0);
    __builtin_amdgcn_s_barrier();
}

// ws layout (float units) — identical to round 6 (935us PASS):
//   [0, 8388608)            Xp2 fp32 [t][k][n][lane][j]   (32 MB)
//                           Hg bf16 [t][ks][b][ul] aliases base (4 MB): Hg[t] writes
//                           (8KB/step) trail Xp2[t] reads (64KB/step) by 8x -> never clobber.
//   [8388608, 8650752)      WihT fp32 (dead after input_proj; prefetch overrun benign)
//   [8650752, 8781824)      Wf bf16 MFMA B-fragments (512 KB)
//   [8781824, 8830976)      feats fp32 [b][t][6]
//   [8830976, 8831488)      flags int[512] (per-block step flags, 64B stride, zeroed per call)

__global__ void transpose_wih(const float* __restrict__ W_ih, float* __restrict__ WihT,
                              int* __restrict__ flags) {
    int o = blockIdx.x * blockDim.x + threadIdx.x;
    if (o < 512) flags[o] = 0;
    if (o >= 256 * 1024) return;
    int k = o >> 10;
    int g = o & 1023;
    WihT[o] = W_ih[g * 256 + k];
}

// Pack W_hh (fp32 [1024][256]) into bf16 MFMA B-fragments.
// flat frag f = ((k*4+n)*8+kt); lane l: g = n*256 + k*16 + (l&15), kk = kt*32 + (l>>4)*8 + j
__global__ void wf_prep(const float* __restrict__ W_hh, unsigned short* __restrict__ Wf) {
    int t = blockIdx.x * 256 + threadIdx.x;  // 0..32767
    int l = t & 63, kt = (t >> 6) & 7, n = (t >> 9) & 3, w = t >> 11;
    int g = n * 256 + w * 16 + (l & 15);
    int kk = kt * 32 + (l >> 4) * 8;
    const float* src = W_hh + g * 256 + kk;
    unsigned short* dst = Wf + (size_t)t * 8;
#pragma unroll
    for (int j = 0; j < 8; j++) dst[j] = bf16_rne(src[j]);
}

// One block = 16 (b,t) rows, 1024 threads = 1 per gate. Writes Xp2 in MFMA C-layout.
__global__ __launch_bounds__(1024) void input_proj(const int* __restrict__ sentence,
                                                   const float* __restrict__ embedding,
                                                   const float* __restrict__ WihT,
                                                   const float* __restrict__ b_ih,
                                                   const float* __restrict__ b_hh,
                                                   float* __restrict__ Xp2) {
    __shared__ __align__(16) float emb[16][260];
    int tid = threadIdx.x;
    int bt0 = blockIdx.x * 16;
    {
        int r = tid >> 6, j = tid & 63;
        int row = sentence[bt0 + r];
        const float4* src = (const float4*)(embedding + (size_t)row * 256);
        float4 v = src[j];
        float* dst = &emb[r][j * 4];
        dst[0] = v.x; dst[1] = v.y; dst[2] = v.z; dst[3] = v.w;
    }
    __syncthreads();
    int g = tid;
    float bias = b_ih[g] + b_hh[g];
    float acc[16];
#pragma unroll
    for (int r = 0; r < 16; r++) acc[r] = bias;
    const float* wp = WihT + g;
    for (int k4 = 0; k4 < 64; k4++) {
        float w0 = wp[(k4 * 4 + 0) * 1024];
        float w1 = wp[(k4 * 4 + 1) * 1024];
        float w2 = wp[(k4 * 4 + 2) * 1024];
        float w3 = wp[(k4 * 4 + 3) * 1024];
#pragma unroll
        for (int r = 0; r < 16; r++) {
            float4 e = *(const float4*)&emb[r][k4 * 4];
            acc[r] += w0 * e.x + w1 * e.y + w2 * e.z + w3 * e.w;
        }
    }
    int b = bt0 >> 9, t0 = bt0 & 511;
    int q = b >> 2, j = b & 3;
    int n = g >> 8, u = g & 255, k = u >> 4, cc = u & 15;
    int lane = q * 16 + cc;
#pragma unroll
    for (int r = 0; r < 16; r++) {
        int t = t0 + r;
        Xp2[(size_t)(((t * 16 + k) * 4 + n) * 64 + lane) * 4 + j] = acc[r];
    }
}

// 16 blocks x 256 threads. Block k owns 64 gate columns (wave n = gate type, 16 cols).
// Round-6 protocol (padded flags, relaxed agent atomics) with the barrier drains removed:
//  - gate-exchange LDS double-buffered by t&1 -> only ONE LDS-only barrier per step;
//  - wave 0 alone drains its h-store acks (vmcnt(0)) then sets the flag; waves 1-3 fall
//    straight into the next spin (flag protocol provides cross-step ordering);
//  - Xp prefetch issued AFTER the drain so it is never on a waitcnt path.
__global__ __launch_bounds__(256) void lstm_mfma(const unsigned short* __restrict__ Wf,
                                                 const float* __restrict__ Xp2,
                                                 unsigned short* __restrict__ Hg,
                                                 int* __restrict__ flags) {
    __shared__ float gl2[2][4][16][16];  // [parity][gate][b][c], 8KB
    int tid = threadIdx.x;
    int k = blockIdx.x;
    int n = tid >> 6;          // wave = gate type (i,f,g,o)
    int l = tid & 63;
    int q = l >> 4;

    // B-fragments of this block's W_hh slice: 8 x short8 = 32 VGPR
    short8 wr[8];
#pragma unroll
    for (int kt = 0; kt < 8; kt++)
        wr[kt] = *(const short8*)(Wf + ((size_t)((k * 4 + n) * 8 + kt) * 64 + l) * 8);

    const char* xbase = (const char*)Xp2 + ((size_t)k * 4 + n) * 1024 + (size_t)l * 16;
    f32x4 xv = *(const f32x4*)xbase;

    // A-frag base within Hg[t] (ull units): row b=(l&15), u = kt*32 + q*8 + j
    // Hg layout [t][ks][b][ul]: ushort addr = ks*256 + b*16 + ul -> /4 for ull index
    int abase_us = (q >> 1) * 256 + (l & 15) * 16 + (q & 1) * 8;
    int abase_ull = abase_us >> 2;

    // c-state: threads 0..63 own 4 h/c values each: b = tid>>2, ul0 = (tid&3)*4
    float c_st[4] = {0.f, 0.f, 0.f, 0.f};
    int b_own = tid >> 2, ul0 = (tid & 3) * 4;

    int* myflag = flags + k * 16;
    int* spinflag = flags + (l & 15) * 16;

    for (int t = 0; t < T; t++) {
        f32x4 acc;
        if (t > 0) {
            // all threads spin: lane l watches flags[l&15]; exit when all >= t
            while (true) {
                int f = __hip_atomic_load(spinflag, __ATOMIC_RELAXED, __HIP_MEMORY_SCOPE_AGENT);
                if (__all(f >= t)) break;
            }
            __builtin_amdgcn_fence(__ATOMIC_ACQUIRE, "workgroup");  // compiler ordering only
            const unsigned long long* hsrc =
                (const unsigned long long*)(Hg + (size_t)(t - 1) * 4096) + abase_ull;
            short8 af[8];
#pragma unroll
            for (int kt = 0; kt < 8; kt++) {
                U16B cv;
                cv.u[0] = __hip_atomic_load(hsrc + kt * 128 + 0, __ATOMIC_RELAXED,
                                            __HIP_MEMORY_SCOPE_AGENT);
                cv.u[1] = __hip_atomic_load(hsrc + kt * 128 + 1, __ATOMIC_RELAXED,
                                            __HIP_MEMORY_SCOPE_AGENT);
                af[kt] = cv.s;
            }
            acc = xv;
#pragma unroll
            for (int kt = 0; kt < 8; kt++)
                acc = __builtin_amdgcn_mfma_f32_16x16x32_bf16(af[kt], wr[kt], acc, 0, 0, 0);
        } else {
            acc = xv;
        }

        // exchange gates across waves into parity buffer: lane (q,c) reg j -> (b=q*4+j, c)
        {
            float(*gl)[16][16] = gl2[t & 1];
            int c = l & 15;
#pragma unroll
            for (int j = 0; j < 4; j++) gl[n][q * 4 + j][c] = acc[j];
        }
        bar_lds();  // gates ready (LDS-only; prefetch/publish queues untouched)

        if (tid < 64) {  // wave 0: c/h update + publish + flag (other waves go to next spin)
            const float(*glr)[16][16] = gl2[t & 1];
            UPK pk;
#pragma unroll
            for (int j = 0; j < 4; j++) {
                float iv = fast_sig(glr[0][b_own][ul0 + j]);
                float fg = fast_sig(glr[1][b_own][ul0 + j]);
                float gv = fast_tanh(glr[2][b_own][ul0 + j]);
                float ov = fast_sig(glr[3][b_own][ul0 + j]);
                c_st[j] = fg * c_st[j] + iv * gv;
                pk.s[j] = bf16_rne(ov * fast_tanh(c_st[j]));
            }
            __hip_atomic_store((unsigned long long*)(Hg + (size_t)t * 4096 + k * 256) + tid,
                               pk.u, __ATOMIC_RELAXED, __HIP_MEMORY_SCOPE_AGENT);
            asm volatile("s_waitcnt vmcnt(0)" ::: "memory");  // drain wave0's h-stores only
            if (tid == 0)
                __hip_atomic_store(myflag, t + 1, __ATOMIC_RELAXED, __HIP_MEMORY_SCOPE_AGENT);
        }

        // prefetch next step's Xp AFTER the drain point -> never on a waitcnt path
        if (t + 1 < T) xv = *(const f32x4*)(xbase + (size_t)(t + 1) * 65536);
    }
}

// feats[b][t][tag] = h(b,t) . W_out[tag] + b_out[tag].  2048 blocks x 256, wave = one (b,t).
__global__ __launch_bounds__(256) void feats_k(const unsigned short* __restrict__ Hg,
                                               const float* __restrict__ W_out,
                                               const float* __restrict__ b_out,
                                               float* __restrict__ feats) {
    int wid = blockIdx.x * 4 + (threadIdx.x >> 6);
    int l = threadIdx.x & 63;
    int b = wid >> 9, t = wid & 511;
    uint2 hv = *(const uint2*)(Hg + (size_t)t * 4096 + (l >> 2) * 256 + b * 16 + (l & 3) * 4);
    float h0 = __builtin_bit_cast(float, (hv.x & 0xffffu) << 16);
    float h1 = __builtin_bit_cast(float, hv.x & 0xffff0000u);
    float h2 = __builtin_bit_cast(float, (hv.y & 0xffffu) << 16);
    float h3 = __builtin_bit_cast(float, hv.y & 0xffff0000u);
    int ub = (l >> 2) * 16 + (l & 3) * 4;
#pragma unroll
    for (int tag = 0; tag < 6; tag++) {
        float4 w = *(const float4*)(W_out + tag * 256 + ub);
        float p = h0 * w.x + h1 * w.y + h2 * w.z + h3 * w.w;
#pragma unroll
        for (int off = 32; off; off >>= 1) p += __shfl_down(p, off);
        if (l == 0) feats[((size_t)b * 512 + t) * 6 + tag] = p + b_out[tag];
    }
}

// 16 blocks x 64 threads. Lane nx owns next-tag nx; fv broadcast via shfl each step.
__global__ __launch_bounds__(64) void crf_scan(const float* __restrict__ feats,
                                               const float* __restrict__ trans,
                                               float* __restrict__ out) {
    __shared__ float fl[T * 6];
    __shared__ unsigned char bp[T * 8];
    int b = blockIdx.x, tid = threadIdx.x;
    const float4* src = (const float4*)(feats + (size_t)b * 3072);
#pragma unroll
    for (int i = 0; i < 12; i++) ((float4*)fl)[tid + i * 64] = src[tid + i * 64];
    int nx = (tid < 6) ? tid : 0;
    float tr0 = trans[nx * 6 + 0], tr1 = trans[nx * 6 + 1], tr2 = trans[nx * 6 + 2],
          tr3 = trans[nx * 6 + 3], tr4 = trans[nx * 6 + 4], tr5 = trans[nx * 6 + 5];
    float fv0 = NEGV, fv1 = NEGV, fv2 = NEGV, fv3 = NEGV, fv4 = 0.f, fv5 = NEGV;  // START=4
    __syncthreads();
    for (int t = 0; t < T; t++) {
        float best = fv0 + tr0; int arg = 0; float s;
        s = fv1 + tr1; if (s > best) { best = s; arg = 1; }
        s = fv2 + tr2; if (s > best) { best = s; arg = 2; }
        s = fv3 + tr3; if (s > best) { best = s; arg = 3; }
        s = fv4 + tr4; if (s > best) { best = s; arg = 4; }
        s = fv5 + tr5; if (s > best) { best = s; arg = 5; }  // strict >: first-max
        float nf = best + fl[t * 6 + nx];
        if (tid < 6) bp[t * 8 + tid] = (unsigned char)arg;
        fv0 = __shfl(nf, 0); fv1 = __shfl(nf, 1); fv2 = __shfl(nf, 2);
        fv3 = __shfl(nf, 3); fv4 = __shfl(nf, 4); fv5 = __shfl(nf, 5);
    }
    __syncthreads();
    if (tid == 0) {
        float best = fv0 + trans[STOP * 6 + 0]; int arg = 0; float s;
        s = fv1 + trans[STOP * 6 + 1]; if (s > best) { best = s; arg = 1; }
        s = fv2 + trans[STOP * 6 + 2]; if (s > best) { best = s; arg = 2; }
        s = fv3 + trans[STOP * 6 + 3]; if (s > best) { best = s; arg = 3; }
        s = fv4 + trans[STOP * 6 + 4]; if (s > best) { best = s; arg = 4; }
        s = fv5 + trans[STOP * 6 + 5]; if (s > best) { best = s; arg = 5; }
        out[b] = best;
        int tag = arg;
        float* paths = out + 16 + (size_t)b * 512;
        for (int t = T - 1; t >= 0; t--) {
            paths[t] = (float)tag;
            tag = bp[t * 8 + tag];
        }
    }
}

extern "C" void kernel_launch(void* const* d_in, const int* in_sizes, int n_in,
                              void* d_out, int out_size, void* d_ws, size_t ws_size,
                              hipStream_t stream) {
    const int* sentence = (const int*)d_in[0];
    const float* embedding = (const float*)d_in[1];
    const float* W_ih = (const float*)d_in[2];
    const float* W_hh = (const float*)d_in[3];
    const float* b_ih = (const float*)d_in[4];
    const float* b_hh = (const float*)d_in[5];
    const float* W_out = (const float*)d_in[6];
    const float* b_out = (const float*)d_in[7];
    const float* trans = (const float*)d_in[8];
    float* out = (float*)d_out;
    float* ws = (float*)d_ws;

    float* Xp2 = ws;
    unsigned short* Hg = (unsigned short*)ws;               // aliases Xp2 (8x trail, safe)
    float* WihT = ws + 8388608;
    unsigned short* Wf = (unsigned short*)(ws + 8650752);
    float* feats = ws + 8781824;
    int* flags = (int*)(ws + 8830976);

    hipLaunchKernelGGL(transpose_wih, dim3(1024), dim3(256), 0, stream, W_ih, WihT, flags);
    hipLaunchKernelGGL(input_proj, dim3(BATCH * T / 16), dim3(1024), 0, stream,
                       sentence, embedding, WihT, b_ih, b_hh, Xp2);
    hipLaunchKernelGGL(wf_prep, dim3(128), dim3(256), 0, stream, W_hh, Wf);
    hipLaunchKernelGGL(lstm_mfma, dim3(NBLK), dim3(256), 0, stream, Wf, Xp2, Hg, flags);
    hipLaunchKernelGGL(feats_k, dim3(2048), dim3(256), 0, stream, Hg, W_out, b_out, feats);
    hipLaunchKernelGGL(crf_scan, dim3(BATCH), dim3(64), 0, stream, feats, trans, out);
}